// Round 1
// baseline (450.889 us; speedup 1.0000x reference)
//
#include <hip/hip_runtime.h>

#define B_ 4
#define C_ 512
#define N_ 4096
#define D_ 64

typedef __attribute__((ext_vector_type(8))) short short8;
typedef __attribute__((ext_vector_type(4))) short short4v;
typedef __attribute__((ext_vector_type(4))) float float4v;

static __device__ __forceinline__ short bfc(float f) {
  unsigned u = __float_as_uint(f);
  u += 0x7FFFu + ((u >> 16) & 1u);   // RNE; inputs are finite
  return (short)(u >> 16);
}

// ---------------------------------------------------------------------------
// Projection kernel: Y = W*x + b for q,k,v; outputs bf16 in MFMA-packed layouts
//   Qt [b][n][64]            (A-operand layout for QK^T: row=i(n), k=d contig)
//   Kpk[b][dt=2][n][dr=32]   (B-operand layout for QK^T: col=j(n), k=d contig)
//   Vpk[b][jt=n/32][c][jr=32](B-operand layout for PV:   col=c,    k=j contig)
// Tile: 64(d) x 128(n) per block, K-loop over C=512. 4 waves = 4 d-rowtiles.
// ---------------------------------------------------------------------------
__global__ __launch_bounds__(256) void proj_kernel(
    const float* __restrict__ xs, const float* __restrict__ xt,
    const float* __restrict__ Wq, const float* __restrict__ bq,
    const float* __restrict__ Wk, const float* __restrict__ bk,
    const float* __restrict__ Wv, const float* __restrict__ bv,
    short* __restrict__ Qt, short* __restrict__ Kpk, short* __restrict__ Vpk)
{
  const int bid = blockIdx.x;
  int mode, b, mt, nt;
  const float *W, *bias, *X;
  if (bid < 128)      { mode = 0; b = bid >> 5;        nt = bid & 31;       mt = 0;            W = Wq; bias = bq; X = xt; }
  else if (bid < 256) { mode = 1; int t = bid - 128; b = t >> 5; nt = t & 31; mt = 0;          W = Wk; bias = bk; X = xs; }
  else                { mode = 2; int t = bid - 256; b = t >> 8; mt = (t >> 5) & 7; nt = t & 31; W = Wv; bias = bv; X = xs; }

  const int tid  = threadIdx.x;
  const int wave = tid >> 6;
  const int lane = tid & 63;
  const int l15  = lane & 15;
  const int g    = lane >> 4;
  const int dbase = mt * 64 + wave * 16;   // wave's 16 output rows
  const int n0 = nt * 128;
  const float* xb = X + (size_t)b * C_ * N_;

  float4v acc[8];
#pragma unroll
  for (int i = 0; i < 8; ++i) acc[i] = (float4v){0.f, 0.f, 0.f, 0.f};

  for (int cs = 0; cs < 16; ++cs) {
    const int c0 = cs * 32;
    // A-frag: W[dbase+l15][c0 + g*8 + 0..7]  (16B-contig fp32 x2)
    const float* wp = W + (size_t)(dbase + l15) * C_ + c0 + g * 8;
    float4v wa = *(const float4v*)wp;
    float4v wb = *(const float4v*)(wp + 4);
    short8 af;
    af[0]=bfc(wa.x); af[1]=bfc(wa.y); af[2]=bfc(wa.z); af[3]=bfc(wa.w);
    af[4]=bfc(wb.x); af[5]=bfc(wb.y); af[6]=bfc(wb.z); af[7]=bfc(wb.w);
#pragma unroll
    for (int ct = 0; ct < 8; ++ct) {
      // B-frag: x[c0+g*8+r][n0+ct*16+l15] (strided scalar; 16 lanes -> 64B segs)
      const float* xp = xb + (size_t)(c0 + g * 8) * N_ + n0 + ct * 16 + l15;
      short8 bf;
#pragma unroll
      for (int r = 0; r < 8; ++r) bf[r] = bfc(xp[(size_t)r * N_]);
      acc[ct] = __builtin_amdgcn_mfma_f32_16x16x32_bf16(af, bf, acc[ct], 0, 0, 0);
    }
  }

  float bv4[4];
#pragma unroll
  for (int r = 0; r < 4; ++r) bv4[r] = bias[dbase + g * 4 + r];

  // C-frag: col n = l15(+16*ct), row d = dbase + g*4 + r  (regs = consecutive d)
  if (mode == 0) {
#pragma unroll
    for (int ct = 0; ct < 8; ++ct) {
      const int n = n0 + ct * 16 + l15;
      short4v pk;
#pragma unroll
      for (int r = 0; r < 4; ++r) pk[r] = bfc(acc[ct][r] + bv4[r]);
      *(short4v*)(Qt + ((size_t)b * N_ + n) * 64 + dbase + g * 4) = pk;
    }
  } else if (mode == 1) {
#pragma unroll
    for (int ct = 0; ct < 8; ++ct) {
      const int n = n0 + ct * 16 + l15;
      short4v pk;
#pragma unroll
      for (int r = 0; r < 4; ++r) pk[r] = bfc(acc[ct][r] + bv4[r]);
      *(short4v*)(Kpk + (((size_t)b * 2 + (dbase >> 5)) * N_ + n) * 32 + (dbase & 31) + g * 4) = pk;
    }
  } else {
#pragma unroll
    for (int ct = 0; ct < 8; ++ct) {
      const int n = n0 + ct * 16 + l15;
      const int jt = n >> 5, jr = n & 31;
      short* vp = Vpk + ((size_t)(b * 128 + jt) * 512) * 32 + jr;
#pragma unroll
      for (int r = 0; r < 4; ++r)
        vp[(size_t)(dbase + g * 4 + r) * 32] = bfc(acc[ct][r] + bv4[r]);
    }
  }
}

// ---------------------------------------------------------------------------
// Flash attention: 1 block per (batch, 64-row q-tile); 8 waves.
// Wave w: S-tiles (rt=w>>1, ct=2*(w&1)+{0,1}); PV c-slice [w*64, w*64+64).
// Online softmax state m/l per row in LDS; rescale skipped unless max grew.
// Epilogue fuses  out = gamma*O/l + x_s.
// ---------------------------------------------------------------------------
__global__ __launch_bounds__(512) void flash_kernel(
    const short* __restrict__ Qt, const short* __restrict__ Kpk, const short* __restrict__ Vpk,
    const float* __restrict__ xs, const float* __restrict__ gp, float* __restrict__ out)
{
  const int bid = blockIdx.x;
  // XCD-aware: batch = xcd>>1 so each batch's K/V stream stays in 2 XCD L2s
  const int xcd = bid & 7, slot = bid >> 3;
  const int b  = xcd >> 1;
  const int qt = (xcd & 1) * 32 + slot;
  const int q0 = qt * 64;

  __shared__ float S_lds[64][68];
  __shared__ short P_lds[64][72];
  __shared__ float m_sm[64], l_sm[64], corr_sm[64];

  const int tid = threadIdx.x;
  const int wave = tid >> 6, lane = tid & 63;
  const int l15 = lane & 15, g = lane >> 4;

  if (tid < 64) { m_sm[tid] = -1e30f; l_sm[tid] = 0.f; }

  const int s_rt  = wave >> 1;
  const int s_ct0 = (wave & 1) * 2;
  short8 qf[2];
  {
    const short* qp = Qt + ((size_t)b * N_ + q0 + s_rt * 16 + l15) * 64 + g * 8;
    qf[0] = *(const short8*)qp;
    qf[1] = *(const short8*)(qp + 32);
  }

  float4v acc[4][4];
#pragma unroll
  for (int i = 0; i < 4; ++i)
#pragma unroll
    for (int j = 0; j < 4; ++j) acc[i][j] = (float4v){0.f,0.f,0.f,0.f};

  const int cb = wave * 64;
  const int srow = tid >> 3, ssub = tid & 7;

  __syncthreads();

  for (int js = 0; js < 64; ++js) {
    const int j0 = js * 64;
    // ---- S = Q·K^T : two 16x16 tiles per wave
#pragma unroll
    for (int t = 0; t < 2; ++t) {
      const int ct = s_ct0 + t;
      const int j  = j0 + ct * 16 + l15;
      const short* kp = Kpk + ((size_t)b * 2 * N_ + j) * 32 + g * 8;
      short8 kf0 = *(const short8*)kp;
      short8 kf1 = *(const short8*)(kp + (size_t)N_ * 32);
      float4v s = (float4v){0.f,0.f,0.f,0.f};
      s = __builtin_amdgcn_mfma_f32_16x16x32_bf16(qf[0], kf0, s, 0, 0, 0);
      s = __builtin_amdgcn_mfma_f32_16x16x32_bf16(qf[1], kf1, s, 0, 0, 0);
#pragma unroll
      for (int r = 0; r < 4; ++r)
        S_lds[s_rt * 16 + g * 4 + r][ct * 16 + l15] = s[r];
    }
    __syncthreads();
    // ---- online softmax over the 64-wide tile (8 threads per row)
    {
      float4v s0 = *(const float4v*)&S_lds[srow][ssub * 8];
      float4v s1 = *(const float4v*)&S_lds[srow][ssub * 8 + 4];
      float mx = fmaxf(fmaxf(fmaxf(s0.x, s0.y), fmaxf(s0.z, s0.w)),
                       fmaxf(fmaxf(s1.x, s1.y), fmaxf(s1.z, s1.w)));
      mx = fmaxf(mx, __shfl_xor(mx, 1));
      mx = fmaxf(mx, __shfl_xor(mx, 2));
      mx = fmaxf(mx, __shfl_xor(mx, 4));
      const float mold = m_sm[srow];
      const float mnew = fmaxf(mold, mx);
      const float cr   = __expf(mold - mnew);
      float p[8];
      p[0]=__expf(s0.x-mnew); p[1]=__expf(s0.y-mnew); p[2]=__expf(s0.z-mnew); p[3]=__expf(s0.w-mnew);
      p[4]=__expf(s1.x-mnew); p[5]=__expf(s1.y-mnew); p[6]=__expf(s1.z-mnew); p[7]=__expf(s1.w-mnew);
      short8 pk;
#pragma unroll
      for (int r = 0; r < 8; ++r) pk[r] = bfc(p[r]);
      *(short8*)&P_lds[srow][ssub * 8] = pk;
      float ls = p[0]+p[1]+p[2]+p[3]+p[4]+p[5]+p[6]+p[7];
      ls += __shfl_xor(ls, 1);
      ls += __shfl_xor(ls, 2);
      ls += __shfl_xor(ls, 4);
      if (ssub == 0) {
        l_sm[srow] = l_sm[srow] * cr + ls;
        m_sm[srow] = mnew;
        corr_sm[srow] = cr;
      }
    }
    __syncthreads();
    // ---- rescale (only if any row's max grew) + O += P·V
    {
      float cr4[4][4];
      int need = 0;
#pragma unroll
      for (int rt = 0; rt < 4; ++rt)
#pragma unroll
        for (int r = 0; r < 4; ++r) {
          cr4[rt][r] = corr_sm[rt * 16 + g * 4 + r];
          need |= (cr4[rt][r] != 1.0f);
        }
      if (__any(need)) {
#pragma unroll
        for (int rt = 0; rt < 4; ++rt)
#pragma unroll
          for (int ct = 0; ct < 4; ++ct)
#pragma unroll
            for (int r = 0; r < 4; ++r) acc[rt][ct][r] *= cr4[rt][r];
      }
#pragma unroll
      for (int kt = 0; kt < 2; ++kt) {
        short8 pa[4];
#pragma unroll
        for (int rt = 0; rt < 4; ++rt)
          pa[rt] = *(const short8*)&P_lds[rt * 16 + l15][kt * 32 + g * 8];
        const short* vp = Vpk + (((size_t)b * 128 + (j0 >> 5) + kt) * 512 + cb) * 32 + g * 8;
#pragma unroll
        for (int ct = 0; ct < 4; ++ct) {
          short8 vb = *(const short8*)(vp + (size_t)(ct * 16 + l15) * 32);
#pragma unroll
          for (int rt = 0; rt < 4; ++rt)
            acc[rt][ct] = __builtin_amdgcn_mfma_f32_16x16x32_bf16(pa[rt], vb, acc[rt][ct], 0, 0, 0);
        }
      }
    }
  }

  // ---- epilogue: out = gamma * O / l + x_s   (regs = consecutive n -> float4)
  const float gm = gp[0];
  float sc[4][4];
#pragma unroll
  for (int rt = 0; rt < 4; ++rt)
#pragma unroll
    for (int r = 0; r < 4; ++r) sc[rt][r] = gm / l_sm[rt * 16 + g * 4 + r];
#pragma unroll
  for (int rt = 0; rt < 4; ++rt)
#pragma unroll
    for (int ct = 0; ct < 4; ++ct) {
      const int c = cb + ct * 16 + l15;
      const size_t base = ((size_t)b * C_ + c) * N_ + q0 + rt * 16 + g * 4;
      float4v xv = *(const float4v*)(xs + base);
      float4v o;
#pragma unroll
      for (int r = 0; r < 4; ++r) o[r] = acc[rt][ct][r] * sc[rt][r] + xv[r];
      *(float4v*)(out + base) = o;
    }
}

extern "C" void kernel_launch(void* const* d_in, const int* in_sizes, int n_in,
                              void* d_out, int out_size, void* d_ws, size_t ws_size,
                              hipStream_t stream) {
  const float* xs = (const float*)d_in[0];
  const float* xt = (const float*)d_in[1];
  const float* Wq = (const float*)d_in[2];
  const float* bq = (const float*)d_in[3];
  const float* Wk = (const float*)d_in[4];
  const float* bk = (const float*)d_in[5];
  const float* Wv = (const float*)d_in[6];
  const float* bv = (const float*)d_in[7];
  const float* gm = (const float*)d_in[8];
  float* out = (float*)d_out;

  char* ws = (char*)d_ws;
  short* Qt  = (short*)(ws);                       // 2 MB
  short* Kpk = (short*)(ws + (size_t)(2 << 20));   // 2 MB
  short* Vpk = (short*)(ws + (size_t)(4 << 20));   // 16 MB

  hipLaunchKernelGGL(proj_kernel, dim3(1280), dim3(256), 0, stream,
                     xs, xt, Wq, bq, Wk, bk, Wv, bv, Qt, Kpk, Vpk);
  hipLaunchKernelGGL(flash_kernel, dim3(256), dim3(512), 0, stream,
                     Qt, Kpk, Vpk, xs, gm, out);
}

// Round 2
// 300.730 us; speedup vs baseline: 1.4993x; 1.4993x over previous
//
#include <hip/hip_runtime.h>

#define B_ 4
#define C_ 512
#define N_ 4096

typedef __attribute__((ext_vector_type(8))) short short8;
typedef __attribute__((ext_vector_type(4))) short short4v;
typedef __attribute__((ext_vector_type(4))) float float4v;

static __device__ __forceinline__ short bfc(float f) {
  unsigned u = __float_as_uint(f);
  u += 0x7FFFu + ((u >> 16) & 1u);   // RNE; inputs are finite
  return (short)(u >> 16);
}

// lgkm-only barrier: LDS producer/consumer ordering without draining vmcnt,
// so register-prefetch global loads stay in flight across the barrier (T4).
static __device__ __forceinline__ void bar_lgkm() {
  asm volatile("s_waitcnt lgkmcnt(0)" ::: "memory");
  __builtin_amdgcn_s_barrier();
  asm volatile("" ::: "memory");
}

// ---------------------------------------------------------------------------
// Projection kernel: Y = W*x + b for q,k,v; outputs bf16 in MFMA-packed layouts
//   Qt [b][n][64]   Kpk[b][dt=2][n][32]   Vpk[b][jt=n/32][c][jr=32]
// x-tile staged to LDS transposed [n][c] bf16 (double-buffered, async-split):
// B-frag = one ds_read_b128. Chunk-XOR swizzle breaks write bank conflicts.
// ---------------------------------------------------------------------------
__global__ __launch_bounds__(256) void proj_kernel(
    const float* __restrict__ xs, const float* __restrict__ xt,
    const float* __restrict__ Wq, const float* __restrict__ bq,
    const float* __restrict__ Wk, const float* __restrict__ bk,
    const float* __restrict__ Wv, const float* __restrict__ bv,
    short* __restrict__ Qt, short* __restrict__ Kpk, short* __restrict__ Vpk)
{
  const int bid = blockIdx.x;
  int mode, b, mt, nt;
  const float *W, *bias, *X;
  if (bid < 128)      { mode = 0; b = bid >> 5;        nt = bid & 31;       mt = 0;            W = Wq; bias = bq; X = xt; }
  else if (bid < 256) { mode = 1; int t = bid - 128; b = t >> 5; nt = t & 31; mt = 0;          W = Wk; bias = bk; X = xs; }
  else                { mode = 2; int t = bid - 256; b = t >> 8; mt = (t >> 5) & 7; nt = t & 31; W = Wv; bias = bv; X = xs; }

  __shared__ short xlds[2][128][40];

  const int tid  = threadIdx.x;
  const int wave = tid >> 6;
  const int lane = tid & 63;
  const int l15  = lane & 15;
  const int g    = lane >> 4;
  const int dbase = mt * 64 + wave * 16;
  const int n0 = nt * 128;
  const float* xb = X + (size_t)b * C_ * N_;

  const int nloc = tid & 127;                       // staging row (constant/thread)
  const int svw  = ((nloc ^ (nloc >> 3)) & 3) << 1; // even XOR on 4-short chunk idx
  const int cgh  = tid >> 7;                        // 0/1

  float v16[16];
  float4v acc[8];
#pragma unroll
  for (int i = 0; i < 8; ++i) acc[i] = (float4v){0.f, 0.f, 0.f, 0.f};

#define XLOAD(CS) { \
    const int c0_ = (CS) * 32; \
    _Pragma("unroll") \
    for (int it_ = 0; it_ < 4; ++it_) { \
      const int cg_ = it_ * 2 + cgh; \
      const float* xp_ = xb + (size_t)(c0_ + cg_ * 4) * N_ + n0 + nloc; \
      _Pragma("unroll") \
      for (int r_ = 0; r_ < 4; ++r_) v16[it_ * 4 + r_] = xp_[(size_t)r_ * N_]; \
    } }

#define XWRITE(BUF) { \
    _Pragma("unroll") \
    for (int it_ = 0; it_ < 4; ++it_) { \
      const int cg_ = it_ * 2 + cgh; \
      short4v pk_; \
      _Pragma("unroll") \
      for (int r_ = 0; r_ < 4; ++r_) pk_[r_] = bfc(v16[it_ * 4 + r_]); \
      *(short4v*)&xlds[BUF][nloc][(cg_ ^ svw) * 4] = pk_; \
    } }

  XLOAD(0);
  XWRITE(0);

  for (int cs = 0; cs < 16; ++cs) {
    __syncthreads();
    if (cs < 15) XLOAD(cs + 1);          // issue early (T14)
    const int pb = cs & 1;
    const float* wp = W + (size_t)(dbase + l15) * C_ + cs * 32 + g * 8;
    float4v wa = *(const float4v*)wp;
    float4v wb2 = *(const float4v*)(wp + 4);
    short8 af;
    af[0]=bfc(wa.x); af[1]=bfc(wa.y); af[2]=bfc(wa.z); af[3]=bfc(wa.w);
    af[4]=bfc(wb2.x); af[5]=bfc(wb2.y); af[6]=bfc(wb2.z); af[7]=bfc(wb2.w);
#pragma unroll
    for (int ct = 0; ct < 8; ++ct) {
      const int nr = ct * 16 + l15;
      const int svr = (nr ^ (nr >> 3)) & 3;
      short8 bf = *(const short8*)&xlds[pb][nr][(g ^ svr) * 8];
      acc[ct] = __builtin_amdgcn_mfma_f32_16x16x32_bf16(af, bf, acc[ct], 0, 0, 0);
    }
    if (cs < 15) XWRITE((cs + 1) & 1);   // write late (T14)
  }

  float bv4[4];
#pragma unroll
  for (int r = 0; r < 4; ++r) bv4[r] = bias[dbase + g * 4 + r];

  if (mode == 0) {
#pragma unroll
    for (int ct = 0; ct < 8; ++ct) {
      const int n = n0 + ct * 16 + l15;
      short4v pk;
#pragma unroll
      for (int r = 0; r < 4; ++r) pk[r] = bfc(acc[ct][r] + bv4[r]);
      *(short4v*)(Qt + ((size_t)b * N_ + n) * 64 + dbase + g * 4) = pk;
    }
  } else if (mode == 1) {
#pragma unroll
    for (int ct = 0; ct < 8; ++ct) {
      const int n = n0 + ct * 16 + l15;
      short4v pk;
#pragma unroll
      for (int r = 0; r < 4; ++r) pk[r] = bfc(acc[ct][r] + bv4[r]);
      *(short4v*)(Kpk + (((size_t)b * 2 + (dbase >> 5)) * N_ + n) * 32 + (dbase & 31) + g * 4) = pk;
    }
  } else {
#pragma unroll
    for (int ct = 0; ct < 8; ++ct) {
      const int n = n0 + ct * 16 + l15;
      const int jt = n >> 5, jr = n & 31;
      short* vp = Vpk + ((size_t)(b * 128 + jt) * 512) * 32 + jr;
#pragma unroll
      for (int r = 0; r < 4; ++r)
        vp[(size_t)(dbase + g * 4 + r) * 32] = bfc(acc[ct][r] + bv4[r]);
    }
  }
#undef XLOAD
#undef XWRITE
}

// ---------------------------------------------------------------------------
// Flash attention: grid 256 (1 block per (batch, 64-row q-tile)), 1024T/16 waves
// (4 waves/SIMD = 50% occupancy). Wave w: one S-tile (rt=w>>2, ct=w&3) and PV
// c-slice [w*32, w*32+32). V register-prefetched one step ahead; lgkm-only
// barriers keep prefetch loads in flight. setprio around PV MFMA cluster (T5).
// Epilogue fuses  out = gamma*O/l + x_s.
// ---------------------------------------------------------------------------
__global__ __launch_bounds__(1024) void flash_kernel(
    const short* __restrict__ Qt, const short* __restrict__ Kpk, const short* __restrict__ Vpk,
    const float* __restrict__ xs, const float* __restrict__ gp, float* __restrict__ out)
{
  const int bid = blockIdx.x;
  const int xcd = bid & 7, slot = bid >> 3;
  const int b  = xcd >> 1;                 // batch pinned to an XCD pair (L2 locality)
  const int qt = (xcd & 1) * 32 + slot;
  const int q0 = qt * 64;

  __shared__ float S_lds[64][68];
  __shared__ short P_lds[64][72];
  __shared__ float m_sm[64], l_sm[64], corr_sm[64];

  const int tid = threadIdx.x;
  const int wave = tid >> 6, lane = tid & 63;
  const int l15 = lane & 15, g = lane >> 4;

  if (tid < 64) { m_sm[tid] = -1e30f; l_sm[tid] = 0.f; }

  const int s_rt = wave >> 2;   // 0..3  S row-tile
  const int s_ct = wave & 3;    // 0..3  S col-tile
  const int cb   = wave * 32;   // PV c-slice base

  short8 qf0, qf1;
  {
    const short* qp = Qt + ((size_t)b * N_ + q0 + s_rt * 16 + l15) * 64 + g * 8;
    qf0 = *(const short8*)qp;
    qf1 = *(const short8*)(qp + 32);
  }

  float4v acc[4][2];
#pragma unroll
  for (int i = 0; i < 4; ++i)
#pragma unroll
    for (int j = 0; j < 2; ++j) acc[i][j] = (float4v){0.f,0.f,0.f,0.f};

  const int srow = tid >> 4, ssub = tid & 15;

  const short* kbase  = Kpk + ((size_t)b * 2 * N_ + s_ct * 16 + l15) * 32 + g * 8;
  const short* vbaseA = Vpk + ((size_t)(b * 128) * 512 + cb + l15) * 32 + g * 8;
  const short* vbaseB = vbaseA + (size_t)16 * 32;

#define VLOAD(V00, V01, V10, V11, JT0) { \
    const size_t off_ = (size_t)(JT0) * (512 * 32); \
    V00 = *(const short8*)(vbaseA + off_); \
    V01 = *(const short8*)(vbaseB + off_); \
    V10 = *(const short8*)(vbaseA + off_ + 512 * 32); \
    V11 = *(const short8*)(vbaseB + off_ + 512 * 32); \
  }

#define MFMA_BF16 __builtin_amdgcn_mfma_f32_16x16x32_bf16

#define STEP(VC00, VC01, VC10, VC11, VN00, VN01, VN10, VN11, JS) { \
    const int j0_ = (JS) * 64; \
    VLOAD(VN00, VN01, VN10, VN11, (((JS) + 1) & 63) * 2)   /* prefetch next V */ \
    { \
      const short* kp_ = kbase + (size_t)j0_ * 32; \
      short8 kf0_ = *(const short8*)kp_; \
      short8 kf1_ = *(const short8*)(kp_ + (size_t)N_ * 32); \
      float4v s_ = (float4v){0.f, 0.f, 0.f, 0.f}; \
      s_ = MFMA_BF16(qf0, kf0_, s_, 0, 0, 0); \
      s_ = MFMA_BF16(qf1, kf1_, s_, 0, 0, 0); \
      _Pragma("unroll") \
      for (int r_ = 0; r_ < 4; ++r_) \
        S_lds[s_rt * 16 + g * 4 + r_][s_ct * 16 + l15] = s_[r_]; \
    } \
    bar_lgkm(); \
    { \
      float4v sv_ = *(const float4v*)&S_lds[srow][ssub * 4]; \
      float mx_ = fmaxf(fmaxf(sv_.x, sv_.y), fmaxf(sv_.z, sv_.w)); \
      mx_ = fmaxf(mx_, __shfl_xor(mx_, 1)); \
      mx_ = fmaxf(mx_, __shfl_xor(mx_, 2)); \
      mx_ = fmaxf(mx_, __shfl_xor(mx_, 4)); \
      mx_ = fmaxf(mx_, __shfl_xor(mx_, 8)); \
      const float mold_ = m_sm[srow]; \
      const float mnew_ = fmaxf(mold_, mx_); \
      const float p0_ = __expf(sv_.x - mnew_), p1_ = __expf(sv_.y - mnew_); \
      const float p2_ = __expf(sv_.z - mnew_), p3_ = __expf(sv_.w - mnew_); \
      short4v pk_; \
      pk_[0] = bfc(p0_); pk_[1] = bfc(p1_); pk_[2] = bfc(p2_); pk_[3] = bfc(p3_); \
      *(short4v*)&P_lds[srow][ssub * 4] = pk_; \
      float ls_ = p0_ + p1_ + p2_ + p3_; \
      ls_ += __shfl_xor(ls_, 1); \
      ls_ += __shfl_xor(ls_, 2); \
      ls_ += __shfl_xor(ls_, 4); \
      ls_ += __shfl_xor(ls_, 8); \
      if (ssub == 0) { \
        const float cr_ = __expf(mold_ - mnew_); \
        l_sm[srow] = l_sm[srow] * cr_ + ls_; \
        m_sm[srow] = mnew_; \
        corr_sm[srow] = cr_; \
      } \
    } \
    bar_lgkm(); \
    { \
      float cr4_[4][4]; \
      int need_ = 0; \
      _Pragma("unroll") \
      for (int rt_ = 0; rt_ < 4; ++rt_) \
        _Pragma("unroll") \
        for (int r_ = 0; r_ < 4; ++r_) { \
          cr4_[rt_][r_] = corr_sm[rt_ * 16 + g * 4 + r_]; \
          need_ |= (cr4_[rt_][r_] != 1.0f); \
        } \
      if (__any(need_)) { \
        _Pragma("unroll") \
        for (int rt_ = 0; rt_ < 4; ++rt_) \
          _Pragma("unroll") \
          for (int ct_ = 0; ct_ < 2; ++ct_) \
            _Pragma("unroll") \
            for (int r_ = 0; r_ < 4; ++r_) acc[rt_][ct_][r_] *= cr4_[rt_][r_]; \
      } \
      __builtin_amdgcn_s_setprio(1); \
      _Pragma("unroll") \
      for (int kt_ = 0; kt_ < 2; ++kt_) { \
        short8 pa_[4]; \
        _Pragma("unroll") \
        for (int rt_ = 0; rt_ < 4; ++rt_) \
          pa_[rt_] = *(const short8*)&P_lds[rt_ * 16 + l15][kt_ * 32 + g * 8]; \
        const short8 vb0_ = kt_ ? VC10 : VC00; \
        const short8 vb1_ = kt_ ? VC11 : VC01; \
        _Pragma("unroll") \
        for (int rt_ = 0; rt_ < 4; ++rt_) { \
          acc[rt_][0] = MFMA_BF16(pa_[rt_], vb0_, acc[rt_][0], 0, 0, 0); \
          acc[rt_][1] = MFMA_BF16(pa_[rt_], vb1_, acc[rt_][1], 0, 0, 0); \
        } \
      } \
      __builtin_amdgcn_s_setprio(0); \
    } \
  }

  short8 a00, a01, a10, a11, b00, b01, b10, b11;
  VLOAD(a00, a01, a10, a11, 0)
  __syncthreads();

  for (int js = 0; js < 64; js += 2) {
    STEP(a00, a01, a10, a11, b00, b01, b10, b11, js)
    STEP(b00, b01, b10, b11, a00, a01, a10, a11, js + 1)
  }
#undef STEP
#undef VLOAD

  // ---- epilogue: out = gamma * O / l + x_s   (regs = consecutive n -> float4)
  const float gm = gp[0];
  float sc[4][4];
#pragma unroll
  for (int rt = 0; rt < 4; ++rt)
#pragma unroll
    for (int r = 0; r < 4; ++r) sc[rt][r] = gm / l_sm[rt * 16 + g * 4 + r];
#pragma unroll
  for (int rt = 0; rt < 4; ++rt)
#pragma unroll
    for (int ct = 0; ct < 2; ++ct) {
      const int c = cb + ct * 16 + l15;
      const size_t base = ((size_t)b * C_ + c) * N_ + q0 + rt * 16 + g * 4;
      float4v xv = *(const float4v*)(xs + base);
      float4v o;
#pragma unroll
      for (int r = 0; r < 4; ++r) o[r] = acc[rt][ct][r] * sc[rt][r] + xv[r];
      *(float4v*)(out + base) = o;
    }
}

extern "C" void kernel_launch(void* const* d_in, const int* in_sizes, int n_in,
                              void* d_out, int out_size, void* d_ws, size_t ws_size,
                              hipStream_t stream) {
  const float* xs = (const float*)d_in[0];
  const float* xt = (const float*)d_in[1];
  const float* Wq = (const float*)d_in[2];
  const float* bq = (const float*)d_in[3];
  const float* Wk = (const float*)d_in[4];
  const float* bk = (const float*)d_in[5];
  const float* Wv = (const float*)d_in[6];
  const float* bv = (const float*)d_in[7];
  const float* gm = (const float*)d_in[8];
  float* out = (float*)d_out;

  char* ws = (char*)d_ws;
  short* Qt  = (short*)(ws);                       // 2 MB
  short* Kpk = (short*)(ws + (size_t)(2 << 20));   // 2 MB
  short* Vpk = (short*)(ws + (size_t)(4 << 20));   // 16 MB

  hipLaunchKernelGGL(proj_kernel, dim3(1280), dim3(256), 0, stream,
                     xs, xt, Wq, bq, Wk, bk, Wv, bv, Qt, Kpk, Vpk);
  hipLaunchKernelGGL(flash_kernel, dim3(256), dim3(1024), 0, stream,
                     Qt, Kpk, Vpk, xs, gm, out);
}